// Round 4
// baseline (1091.723 us; speedup 1.0000x reference)
//
#include <hip/hip_runtime.h>
#include <hip/hip_bf16.h>
#include <cstddef>
#include <cstdint>

// ---------------------------------------------------------------------------
// StandardPartitionAttention — round 5:
//  * attn_fused2_k: QKV-gen + attention + out-proj + residual + LN2 all in one
//    block per window (o stays in LDS, overlaid on dead h-stage region).
//  * mlp_fused_k: MLP1 + ReLU + W2 + residual (+ LN1 of next layer) in one
//    kernel; mid activations live in LDS (kills the 268 MB hid round-trip).
//  * 8 launches total (was 13).
// ---------------------------------------------------------------------------

#define ROWS      65536
#define DMODEL    256
#define NWIN      1024
#define NHEADS    8
#define QKV_N     768
#define MLP_N     1024
#define SCALE_F   0.17677669529663687f
#define LN_EPS_F  1e-5f

typedef float f32x4 __attribute__((ext_vector_type(4)));
typedef __bf16 bf16x8 __attribute__((ext_vector_type(8)));

#define CP16(gp, lp)                                                          \
  __builtin_amdgcn_global_load_lds(                                           \
      (const __attribute__((address_space(1))) unsigned int*)(gp),            \
      (__attribute__((address_space(3))) unsigned int*)(lp), 16, 0, 0)

// ---------------- window gather: x[B,C,H,W] -> Xg[row, c] (bf16) ------------
__global__ __launch_bounds__(256) void gather_k(const float* __restrict__ x,
                                                ushort* __restrict__ Xg) {
  __shared__ float tile[64 * 132];
  const int tid = threadIdx.x;
  const int bid = blockIdx.x;
  const int chunk = bid & 3;
  const int y = (bid >> 2) & 127;
  const int b = bid >> 9;
  const int c0 = chunk << 6;
  {
    const int x4 = tid & 31, cr = tid >> 5;
#pragma unroll
    for (int p = 0; p < 8; ++p) {
      const int cl = cr + p * 8;
      const float4 v = *(const float4*)(x +
          ((((size_t)b * 256 + c0 + cl) * 128 + y) * 128 + x4 * 4));
      *(float4*)(tile + cl * 132 + x4 * 4) = v;
    }
  }
  __syncthreads();
  {
    const int xx = tid >> 1, half = tid & 1;
    union { ushort s[32]; uint4 q[4]; } U;
#pragma unroll
    for (int cp = 0; cp < 32; ++cp) {
      const float v = tile[(half * 32 + cp) * 132 + xx];
      U.s[cp] = ((__hip_bfloat16_raw)__float2bfloat16(v)).x;
    }
    const int row = ((b * 16 + (y >> 3)) * 16 + (xx >> 3)) * 64 +
                    (y & 7) * 8 + (xx & 7);
    uint4* dst = (uint4*)(Xg + (size_t)row * 256 + c0 + half * 32);
#pragma unroll
    for (int z = 0; z < 4; ++z) dst[z] = U.q[z];
  }
}

// ---------------- un-window: t[row, d] -> out[B,D,H,W] ----------------------
__global__ __launch_bounds__(256) void unwindow_k(const float* __restrict__ t,
                                                  float* __restrict__ out) {
  __shared__ float tile[128 * 65];
  const int tid = threadIdx.x;
  const int bid = blockIdx.x;
  const int dchunk = bid & 3;
  const int y = (bid >> 2) & 127;
  const int b = bid >> 9;
  const int d0 = dchunk << 6;
  {
    const int d4 = tid & 15, xr = tid >> 4;
#pragma unroll
    for (int p = 0; p < 8; ++p) {
      const int xx = xr + p * 16;
      const int row = ((b * 16 + (y >> 3)) * 16 + (xx >> 3)) * 64 +
                      (y & 7) * 8 + (xx & 7);
      const float4 v = *(const float4*)(t + (size_t)row * 256 + d0 + d4 * 4);
      tile[xx * 65 + d4 * 4 + 0] = v.x;
      tile[xx * 65 + d4 * 4 + 1] = v.y;
      tile[xx * 65 + d4 * 4 + 2] = v.z;
      tile[xx * 65 + d4 * 4 + 3] = v.w;
    }
  }
  __syncthreads();
  {
    const int xx = tid & 127, dd = tid >> 7;
#pragma unroll
    for (int p = 0; p < 32; ++p) {
      const int d = p * 2 + dd;
      out[(((size_t)b * 256 + d0 + d) * 128 + y) * 128 + xx] =
          tile[xx * 65 + d];
    }
  }
}

// ---------------- all weight transposes in one launch -----------------------
__global__ __launch_bounds__(256) void transpose_all_k(
    const float* __restrict__ Wp, const float* __restrict__ Wqkv,
    const float* __restrict__ Wo, const float* __restrict__ W1,
    const float* __restrict__ W2, ushort* __restrict__ WpT,
    ushort* __restrict__ WqkvT, ushort* __restrict__ WoT,
    ushort* __restrict__ W1T, ushort* __restrict__ W2T) {
  __shared__ float tile[32][33];
  const int bid = blockIdx.x;
  const float* src; ushort* dst; int K, N, r;
  if (bid < 64) { src = Wp; dst = WpT; K = 256; N = 256; r = bid; }
  else {
    const int tt = bid - 64, l = tt / 768; r = tt % 768;
    if (r < 192)      { src = Wqkv + (size_t)l * 196608; dst = WqkvT + (size_t)l * 196608; K = 256; N = 768; }
    else if (r < 256) { src = Wo + (size_t)l * 65536;  dst = WoT + (size_t)l * 65536;  K = 256; N = 256;  r -= 192; }
    else if (r < 512) { src = W1 + (size_t)l * 262144; dst = W1T + (size_t)l * 262144; K = 256; N = 1024; r -= 256; }
    else              { src = W2 + (size_t)l * 262144; dst = W2T + (size_t)l * 262144; K = 1024; N = 256; r -= 512; }
  }
  const int nx = N >> 5;
  const int n0 = (r % nx) * 32, k0 = (r / nx) * 32;
  const int tx = threadIdx.x & 31, ty = threadIdx.x >> 5;
#pragma unroll
  for (int i = 0; i < 4; ++i)
    tile[ty + i * 8][tx] = src[(size_t)(k0 + ty + i * 8) * N + n0 + tx];
  __syncthreads();
#pragma unroll
  for (int i = 0; i < 4; ++i)
    dst[(size_t)(n0 + ty + i * 8) * K + k0 + tx] =
        ((__hip_bfloat16_raw)__float2bfloat16(tile[tx][ty + i * 8])).x;
}

// ---------------- GEMM (N=256, tile 64x256, BK=64) + fused LayerNorm --------
// (used only for patch embed + LN1 of layer 0)
template <bool RES>
__global__ __launch_bounds__(256) void mm_ln_k(const ushort* __restrict__ A,
                                               const ushort* __restrict__ BT,
                                               const float* __restrict__ bias,
                                               const float* __restrict__ res,
                                               float* __restrict__ Tout,
                                               __hip_bfloat16* __restrict__ Hout,
                                               const float* __restrict__ g,
                                               const float* __restrict__ bb,
                                               int K) {
  __shared__ ushort As[4096];
  __shared__ ushort Bs[16384];
  __shared__ float rs[64][4], rs2[64][4];
  const int tid = threadIdx.x;
  const int bm = blockIdx.x << 6;
  const ushort* Ap = A + (size_t)(bm + (tid >> 2)) * K + ((tid & 3) << 3);
  const ushort* Bp = BT + (size_t)(tid >> 2) * K + ((tid & 3) << 3);
  const size_t k64 = (size_t)64 * K;
  const int lane = tid & 63, wave = tid >> 6;
  const int l15 = lane & 15, quad = lane >> 4;
  const ushort* aF = &As[l15 * 32 + quad * 8];
  const ushort* bF = &Bs[(wave * 64 + l15) * 32 + quad * 8];
  f32x4 acc[4][4] = {};
  for (int k0 = 0; k0 < K; k0 += 64) {
    __syncthreads();
    CP16(Ap, &As[tid * 8]);
    CP16(Ap + 32, &As[2048 + tid * 8]);
#pragma unroll
    for (int cb = 0; cb < 4; ++cb) {
      CP16(Bp + cb * k64, &Bs[cb * 2048 + tid * 8]);
      CP16(Bp + cb * k64 + 32, &Bs[8192 + cb * 2048 + tid * 8]);
    }
    Ap += 64; Bp += 64;
    __syncthreads();
#pragma unroll
    for (int c = 0; c < 2; ++c) {
      bf16x8 af[4], bf[4];
#pragma unroll
      for (int i = 0; i < 4; ++i) af[i] = *(const bf16x8*)(aF + c * 2048 + i * 512);
#pragma unroll
      for (int j = 0; j < 4; ++j) bf[j] = *(const bf16x8*)(bF + c * 8192 + j * 512);
#pragma unroll
      for (int i = 0; i < 4; ++i)
#pragma unroll
        for (int j = 0; j < 4; ++j)
          acc[i][j] =
              __builtin_amdgcn_mfma_f32_16x16x32_bf16(af[i], bf[j], acc[i][j], 0, 0, 0);
    }
  }
  const int rb = quad * 4;
#pragma unroll
  for (int i = 0; i < 4; ++i)
#pragma unroll
    for (int j = 0; j < 4; ++j) {
      const int col = wave * 64 + j * 16 + l15;
      const float bv = bias[col];
#pragma unroll
      for (int r = 0; r < 4; ++r) {
        const int row = bm + i * 16 + rb + r;
        float x = acc[i][j][r] + bv;
        if (RES) x += res[(size_t)row * 256 + col];
        acc[i][j][r] = x;
      }
    }
#pragma unroll
  for (int i = 0; i < 4; ++i)
#pragma unroll
    for (int r = 0; r < 4; ++r) {
      float s = 0.f, s2 = 0.f;
#pragma unroll
      for (int j = 0; j < 4; ++j) {
        float x = acc[i][j][r];
        s += x; s2 += x * x;
      }
      s += __shfl_xor(s, 1);  s += __shfl_xor(s, 2);
      s += __shfl_xor(s, 4);  s += __shfl_xor(s, 8);
      s2 += __shfl_xor(s2, 1); s2 += __shfl_xor(s2, 2);
      s2 += __shfl_xor(s2, 4); s2 += __shfl_xor(s2, 8);
      if (l15 == 0) {
        rs[i * 16 + rb + r][wave] = s;
        rs2[i * 16 + rb + r][wave] = s2;
      }
    }
  __syncthreads();
  float mrow[4][4], rrow[4][4];
#pragma unroll
  for (int i = 0; i < 4; ++i)
#pragma unroll
    for (int r = 0; r < 4; ++r) {
      const int lr = i * 16 + rb + r;
      float4 s4 = *(const float4*)rs[lr];
      float4 q4 = *(const float4*)rs2[lr];
      float tot = s4.x + s4.y + s4.z + s4.w;
      float tot2 = q4.x + q4.y + q4.z + q4.w;
      float m = tot * (1.0f / 256.0f);
      float var = tot2 * (1.0f / 256.0f) - m * m;
      mrow[i][r] = m;
      rrow[i][r] = rsqrtf(var + LN_EPS_F);
    }
#pragma unroll
  for (int i = 0; i < 4; ++i)
#pragma unroll
    for (int j = 0; j < 4; ++j) {
      const int col = wave * 64 + j * 16 + l15;
      const float gv = g[col], bv = bb[col];
#pragma unroll
      for (int r = 0; r < 4; ++r) {
        const int row = bm + i * 16 + rb + r;
        float x = acc[i][j][r];
        Tout[(size_t)row * 256 + col] = x;
        Hout[(size_t)row * 256 + col] =
            __float2bfloat16((x - mrow[i][r]) * rrow[i][r] * gv + bv);
      }
    }
}

// ---------------- fused QKV + attention + out-proj + residual + LN2 ---------
// Block = 1 window, 512 thr, 8 waves = 8 heads. o never leaves LDS.
__global__ __launch_bounds__(512) void attn_fused2_k(
    const ushort* __restrict__ h,       // [65536][256] bf16 (LN1 out; rewritten as LN2 out)
    const ushort* __restrict__ WqkvT,   // [768][256]
    const ushort* __restrict__ WoutT,   // [256][256]
    const float* __restrict__ bout,
    float* __restrict__ t,              // residual stream (read+write)
    __hip_bfloat16* __restrict__ Hout,  // = h buffer (LN2 output)
    const float* __restrict__ g,
    const float* __restrict__ bb,
    float* __restrict__ attns_out,
    const float* __restrict__ bias_tbl,
    const float* __restrict__ sita_l) {
  __shared__ ushort hs[64 * 256];       // 32 KB; later overlaid by o (swizzled)
  __shared__ ushort smem[8 * 7424];     // 116 KB per-wave q/k/vT/P
  __shared__ float tbl[8][225];         // 7.2 KB
  __shared__ float rs[64][8], rs2[64][8]; // 4 KB LN2 partials
  const int tid = threadIdx.x;
  const int lane = tid & 63, wave = tid >> 6;
  const int w = blockIdx.x;
  const int head = wave;
  ushort* qw = smem + wave * 7424;
  ushort* kw = qw + 2560;
  ushort* vw = kw + 2560;
  ushort* Pw = qw;

  for (int idx = tid; idx < 8 * 225; idx += 512) {
    const int hh = idx / 225, e = idx - hh * 225;
    const float sita = sita_l[hh];
    const float factor = 1.0f / (2.0f * sita * sita + 1e-10f);
    const int dyi = e / 15 - 7, dxi = e % 15 - 7;
    const float dis = (float)(dyi * dyi + dxi * dxi) * 0.015625f;
    tbl[hh][e] = bias_tbl[e * NHEADS + hh] + 0.01f * __expf(-factor * dis);
  }

  // stage h window -> LDS, source pre-swizzled (rule 21)
  {
    const char* hb = (const char*)(h + (size_t)w * 64 * 256);
#pragma unroll
    for (int p = 0; p < 4; ++p) {
      const int off = p * 8192 + tid * 16;
      const int row = off >> 9;
      const int col = (off & 511) ^ ((row & 7) << 4);
      CP16(hb + row * 512 + col, (char*)hs + off);
    }
  }
  __syncthreads();

  const int l15 = lane & 15, quad = lane >> 4;

  // ---- q/k/v generation ----
  {
    const ushort* Wq = WqkvT + (size_t)(head * 32) * 256;
    const ushort* Wk = WqkvT + (size_t)(256 + head * 32) * 256;
    const ushort* Wv = WqkvT + (size_t)(512 + head * 32) * 256;
    f32x4 qa[4][2] = {}, ka[4][2] = {}, va[4][2] = {};
#pragma unroll
    for (int k0 = 0; k0 < 256; k0 += 32) {
      bf16x8 af[4], bq[2], bk[2], bv[2];
#pragma unroll
      for (int i = 0; i < 4; ++i) {
        const int row = i * 16 + l15;
        const int cb = (k0 * 2 + quad * 16) ^ ((row & 7) << 4);
        af[i] = *(const bf16x8*)((const char*)hs + row * 512 + cb);
      }
#pragma unroll
      for (int j = 0; j < 2; ++j) {
        const int nro = (j * 16 + l15) * 256 + k0 + quad * 8;
        bq[j] = *(const bf16x8*)(Wq + nro);
        bk[j] = *(const bf16x8*)(Wk + nro);
        bv[j] = *(const bf16x8*)(Wv + nro);
      }
#pragma unroll
      for (int i = 0; i < 4; ++i)
#pragma unroll
        for (int j = 0; j < 2; ++j) {
          qa[i][j] = __builtin_amdgcn_mfma_f32_16x16x32_bf16(af[i], bq[j], qa[i][j], 0, 0, 0);
          ka[i][j] = __builtin_amdgcn_mfma_f32_16x16x32_bf16(af[i], bk[j], ka[i][j], 0, 0, 0);
          va[i][j] = __builtin_amdgcn_mfma_f32_16x16x32_bf16(af[i], bv[j], va[i][j], 0, 0, 0);
        }
    }
#pragma unroll
    for (int i = 0; i < 4; ++i)
#pragma unroll
      for (int j = 0; j < 2; ++j)
#pragma unroll
        for (int r = 0; r < 4; ++r) {
          const int row = i * 16 + quad * 4 + r;
          const int col = j * 16 + l15;
          qw[row * 40 + col] = ((__hip_bfloat16_raw)__float2bfloat16(qa[i][j][r])).x;
          kw[row * 40 + col] = ((__hip_bfloat16_raw)__float2bfloat16(ka[i][j][r])).x;
          vw[col * 72 + row] = ((__hip_bfloat16_raw)__float2bfloat16(va[i][j][r])).x;
        }
  }

  // ---- QK^T ----
  f32x4 acc[4][4] = {};
  {
    bf16x8 af[4], bfr[4];
#pragma unroll
    for (int i = 0; i < 4; ++i)
      af[i] = *(const bf16x8*)(qw + (i * 16 + l15) * 40 + quad * 8);
#pragma unroll
    for (int j = 0; j < 4; ++j)
      bfr[j] = *(const bf16x8*)(kw + (j * 16 + l15) * 40 + quad * 8);
#pragma unroll
    for (int i = 0; i < 4; ++i)
#pragma unroll
      for (int j = 0; j < 4; ++j)
        acc[i][j] =
            __builtin_amdgcn_mfma_f32_16x16x32_bf16(af[i], bfr[j], acc[i][j], 0, 0, 0);
  }

  // scores
  float e1[4][4][4];
#pragma unroll
  for (int i = 0; i < 4; ++i)
#pragma unroll
    for (int r = 0; r < 4; ++r) {
      const int row = i * 16 + quad * 4 + r;
      const int iy = row >> 3, ix = row & 7;
#pragma unroll
      for (int j = 0; j < 4; ++j) {
        const int col = j * 16 + l15;
        const int jy = col >> 3, jx = col & 7;
        float d0 = acc[i][j][r] * SCALE_F;
        acc[i][j][r] = d0;
        e1[i][j][r] = d0 + tbl[head][(iy - jy + 7) * 15 + (ix - jx + 7)];
      }
    }

  // dual softmax per row
#pragma unroll
  for (int i = 0; i < 4; ++i)
#pragma unroll
    for (int r = 0; r < 4; ++r) {
      float m0 = -1e30f, m1 = -1e30f;
#pragma unroll
      for (int j = 0; j < 4; ++j) {
        m0 = fmaxf(m0, acc[i][j][r]);
        m1 = fmaxf(m1, e1[i][j][r]);
      }
      m0 = fmaxf(m0, __shfl_xor(m0, 1)); m0 = fmaxf(m0, __shfl_xor(m0, 2));
      m0 = fmaxf(m0, __shfl_xor(m0, 4)); m0 = fmaxf(m0, __shfl_xor(m0, 8));
      m1 = fmaxf(m1, __shfl_xor(m1, 1)); m1 = fmaxf(m1, __shfl_xor(m1, 2));
      m1 = fmaxf(m1, __shfl_xor(m1, 4)); m1 = fmaxf(m1, __shfl_xor(m1, 8));
      float z0 = 0.f, z1 = 0.f;
#pragma unroll
      for (int j = 0; j < 4; ++j) {
        float a = __expf(acc[i][j][r] - m0); acc[i][j][r] = a; z0 += a;
        float bqq = __expf(e1[i][j][r] - m1); e1[i][j][r] = bqq; z1 += bqq;
      }
      z0 += __shfl_xor(z0, 1); z0 += __shfl_xor(z0, 2);
      z0 += __shfl_xor(z0, 4); z0 += __shfl_xor(z0, 8);
      z1 += __shfl_xor(z1, 1); z1 += __shfl_xor(z1, 2);
      z1 += __shfl_xor(z1, 4); z1 += __shfl_xor(z1, 8);
      const float r0i = 1.f / z0, r1i = 1.f / z1;
#pragma unroll
      for (int j = 0; j < 4; ++j) {
        acc[i][j][r] *= r0i;
        e1[i][j][r] *= r1i;
      }
    }

  // attns (softmax of dots0) -> d_out
  {
    float* ab = attns_out + ((size_t)(w * NHEADS + head)) * 4096;
#pragma unroll
    for (int i = 0; i < 4; ++i)
#pragma unroll
      for (int j = 0; j < 4; ++j)
#pragma unroll
        for (int r = 0; r < 4; ++r)
          ab[(i * 16 + quad * 4 + r) * 64 + j * 16 + l15] = acc[i][j][r];
  }

  // P -> LDS row-major bf16
#pragma unroll
  for (int i = 0; i < 4; ++i)
#pragma unroll
    for (int j = 0; j < 4; ++j)
#pragma unroll
      for (int r = 0; r < 4; ++r)
        Pw[(i * 16 + quad * 4 + r) * 72 + j * 16 + l15] =
            ((__hip_bfloat16_raw)__float2bfloat16(e1[i][j][r])).x;

  // AV: O = P @ V
  f32x4 oacc[4][2] = {};
#pragma unroll
  for (int ks = 0; ks < 2; ++ks) {
    bf16x8 pa[4], vb[2];
#pragma unroll
    for (int i = 0; i < 4; ++i)
      pa[i] = *(const bf16x8*)(Pw + (i * 16 + l15) * 72 + ks * 32 + quad * 8);
#pragma unroll
    for (int j = 0; j < 2; ++j)
      vb[j] = *(const bf16x8*)(vw + (j * 16 + l15) * 72 + ks * 32 + quad * 8);
#pragma unroll
    for (int i = 0; i < 4; ++i)
#pragma unroll
      for (int j = 0; j < 2; ++j)
        oacc[i][j] =
            __builtin_amdgcn_mfma_f32_16x16x32_bf16(pa[i], vb[j], oacc[i][j], 0, 0, 0);
  }

  // ---- out-proj + residual + LN2 (o overlaid on hs, swizzled) ----
  ushort* os = hs;
  __syncthreads();   // all waves done reading hs
#pragma unroll
  for (int i = 0; i < 4; ++i)
#pragma unroll
    for (int j = 0; j < 2; ++j)
#pragma unroll
      for (int r = 0; r < 4; ++r) {
        const int row = i * 16 + quad * 4 + r;
        const int col = head * 32 + j * 16 + l15;
        os[row * 256 + (col ^ ((row & 7) << 3))] =
            ((__hip_bfloat16_raw)__float2bfloat16(oacc[i][j][r])).x;
      }
  __syncthreads();

  f32x4 pacc[4][2] = {};
#pragma unroll
  for (int ks = 0; ks < 8; ++ks) {
    bf16x8 af[4], bw[2];
#pragma unroll
    for (int i = 0; i < 4; ++i) {
      const int row = i * 16 + l15;
      const int cu = (ks * 32 + quad * 8) ^ ((row & 7) << 3);
      af[i] = *(const bf16x8*)(os + row * 256 + cu);
    }
#pragma unroll
    for (int j = 0; j < 2; ++j)
      bw[j] = *(const bf16x8*)(WoutT +
          (size_t)(wave * 32 + j * 16 + l15) * 256 + ks * 32 + quad * 8);
#pragma unroll
    for (int i = 0; i < 4; ++i)
#pragma unroll
      for (int j = 0; j < 2; ++j)
        pacc[i][j] =
            __builtin_amdgcn_mfma_f32_16x16x32_bf16(af[i], bw[j], pacc[i][j], 0, 0, 0);
  }

  // bias + residual; LN2 partials (8 waves x 32 cols)
  float* tw = t + (size_t)(w * 64) * 256;
#pragma unroll
  for (int i = 0; i < 4; ++i)
#pragma unroll
    for (int r = 0; r < 4; ++r) {
      const int row = i * 16 + quad * 4 + r;
      float s = 0.f, s2 = 0.f;
#pragma unroll
      for (int j = 0; j < 2; ++j) {
        const int col = wave * 32 + j * 16 + l15;
        float xx = pacc[i][j][r] + bout[col] + tw[row * 256 + col];
        pacc[i][j][r] = xx;
        s += xx; s2 += xx * xx;
      }
      s += __shfl_xor(s, 1);  s += __shfl_xor(s, 2);
      s += __shfl_xor(s, 4);  s += __shfl_xor(s, 8);
      s2 += __shfl_xor(s2, 1); s2 += __shfl_xor(s2, 2);
      s2 += __shfl_xor(s2, 4); s2 += __shfl_xor(s2, 8);
      if (l15 == 0) { rs[row][wave] = s; rs2[row][wave] = s2; }
    }
  __syncthreads();
  ushort* hw = (ushort*)Hout + (size_t)(w * 64) * 256;
#pragma unroll
  for (int i = 0; i < 4; ++i)
#pragma unroll
    for (int r = 0; r < 4; ++r) {
      const int row = i * 16 + quad * 4 + r;
      float4 a4 = *(const float4*)&rs[row][0];
      float4 b4 = *(const float4*)&rs[row][4];
      float4 c4 = *(const float4*)&rs2[row][0];
      float4 d4 = *(const float4*)&rs2[row][4];
      const float tot = a4.x + a4.y + a4.z + a4.w + b4.x + b4.y + b4.z + b4.w;
      const float tot2 = c4.x + c4.y + c4.z + c4.w + d4.x + d4.y + d4.z + d4.w;
      const float m = tot * (1.0f / 256.0f);
      const float var = tot2 * (1.0f / 256.0f) - m * m;
      const float rr = rsqrtf(var + LN_EPS_F);
#pragma unroll
      for (int j = 0; j < 2; ++j) {
        const int col = wave * 32 + j * 16 + l15;
        const float xx = pacc[i][j][r];
        tw[row * 256 + col] = xx;
        hw[row * 256 + col] = ((__hip_bfloat16_raw)__float2bfloat16(
            (xx - m) * rr * g[col] + bb[col])).x;
      }
    }
}

// ---------------- fused MLP: relu(h@W1+b1)@W2 + b2 + t (+LN) ----------------
// Block = 64 rows, 256 thr (4 waves). mid chunks of 256 live in LDS.
template <bool DOLN>
__global__ __launch_bounds__(256) void mlp_fused_k(
    const ushort* __restrict__ h, const ushort* __restrict__ W1T,
    const float* __restrict__ b1, const ushort* __restrict__ W2T,
    const float* __restrict__ b2, float* __restrict__ t,
    __hip_bfloat16* __restrict__ Hout, const float* __restrict__ g,
    const float* __restrict__ bb) {
  __shared__ ushort hs[64 * 256];   // 32 KB swizzled
  __shared__ ushort mid[64 * 256];  // 32 KB swizzled
  __shared__ float rs[64][4], rs2[64][4];
  const int tid = threadIdx.x;
  const int lane = tid & 63, wave = tid >> 6;
  const int l15 = lane & 15, quad = lane >> 4;
  const int bm = blockIdx.x << 6;
  {
    const char* hb = (const char*)(h + (size_t)bm * 256);
#pragma unroll
    for (int p = 0; p < 8; ++p) {
      const int off = p * 4096 + tid * 16;
      const int row = off >> 9;
      const int col = (off & 511) ^ ((row & 7) << 4);
      CP16(hb + row * 512 + col, (char*)hs + off);
    }
  }
  __syncthreads();

  f32x4 cacc[4][4] = {};
  for (int ch = 0; ch < 4; ++ch) {
    // mid chunk: cols ch*256 + wave*64 + [0,64)
    f32x4 macc[4][4] = {};
#pragma unroll
    for (int ks = 0; ks < 8; ++ks) {
      bf16x8 af[4], bf[4];
#pragma unroll
      for (int i = 0; i < 4; ++i) {
        const int row = i * 16 + l15;
        const int cb = (ks * 64 + quad * 16) ^ ((row & 7) << 4);
        af[i] = *(const bf16x8*)((const char*)hs + row * 512 + cb);
      }
#pragma unroll
      for (int j = 0; j < 4; ++j)
        bf[j] = *(const bf16x8*)(W1T +
            (size_t)(ch * 256 + wave * 64 + j * 16 + l15) * 256 + ks * 32 + quad * 8);
#pragma unroll
      for (int i = 0; i < 4; ++i)
#pragma unroll
        for (int j = 0; j < 4; ++j)
          macc[i][j] =
              __builtin_amdgcn_mfma_f32_16x16x32_bf16(af[i], bf[j], macc[i][j], 0, 0, 0);
    }
    __syncthreads();   // prev chunk's mid reads complete
#pragma unroll
    for (int i = 0; i < 4; ++i)
#pragma unroll
      for (int j = 0; j < 4; ++j) {
        const int col = wave * 64 + j * 16 + l15;
        const float bv = b1[ch * 256 + col];
#pragma unroll
        for (int r = 0; r < 4; ++r) {
          const int row = i * 16 + quad * 4 + r;
          const float v = fmaxf(macc[i][j][r] + bv, 0.f);
          mid[row * 256 + (col ^ ((row & 7) << 3))] =
              ((__hip_bfloat16_raw)__float2bfloat16(v)).x;
        }
      }
    __syncthreads();   // mid visible
#pragma unroll
    for (int ks = 0; ks < 8; ++ks) {
      bf16x8 am[4], bw[4];
#pragma unroll
      for (int i = 0; i < 4; ++i) {
        const int row = i * 16 + l15;
        const int cu = (ks * 32 + quad * 8) ^ ((row & 7) << 3);
        am[i] = *(const bf16x8*)(mid + row * 256 + cu);
      }
#pragma unroll
      for (int j = 0; j < 4; ++j)
        bw[j] = *(const bf16x8*)(W2T +
            (size_t)(wave * 64 + j * 16 + l15) * 1024 + ch * 256 + ks * 32 + quad * 8);
#pragma unroll
      for (int i = 0; i < 4; ++i)
#pragma unroll
        for (int j = 0; j < 4; ++j)
          cacc[i][j] =
              __builtin_amdgcn_mfma_f32_16x16x32_bf16(am[i], bw[j], cacc[i][j], 0, 0, 0);
    }
  }

  // epilogue: + b2 + residual; write t; optional LN -> Hout
  const int rb = quad * 4;
#pragma unroll
  for (int i = 0; i < 4; ++i)
#pragma unroll
    for (int j = 0; j < 4; ++j) {
      const int col = wave * 64 + j * 16 + l15;
      const float bv = b2[col];
#pragma unroll
      for (int r = 0; r < 4; ++r) {
        const int row = bm + i * 16 + rb + r;
        float x = cacc[i][j][r] + bv + t[(size_t)row * 256 + col];
        cacc[i][j][r] = x;
      }
    }
  if (DOLN) {
#pragma unroll
    for (int i = 0; i < 4; ++i)
#pragma unroll
      for (int r = 0; r < 4; ++r) {
        float s = 0.f, s2 = 0.f;
#pragma unroll
        for (int j = 0; j < 4; ++j) {
          float x = cacc[i][j][r];
          s += x; s2 += x * x;
        }
        s += __shfl_xor(s, 1);  s += __shfl_xor(s, 2);
        s += __shfl_xor(s, 4);  s += __shfl_xor(s, 8);
        s2 += __shfl_xor(s2, 1); s2 += __shfl_xor(s2, 2);
        s2 += __shfl_xor(s2, 4); s2 += __shfl_xor(s2, 8);
        if (l15 == 0) {
          rs[i * 16 + rb + r][wave] = s;
          rs2[i * 16 + rb + r][wave] = s2;
        }
      }
    __syncthreads();
#pragma unroll
    for (int i = 0; i < 4; ++i)
#pragma unroll
      for (int r = 0; r < 4; ++r) {
        const int lr = i * 16 + rb + r;
        float4 s4 = *(const float4*)rs[lr];
        float4 q4 = *(const float4*)rs2[lr];
        const float tot = s4.x + s4.y + s4.z + s4.w;
        const float tot2 = q4.x + q4.y + q4.z + q4.w;
        const float m = tot * (1.0f / 256.0f);
        const float var = tot2 * (1.0f / 256.0f) - m * m;
        const float rr = rsqrtf(var + LN_EPS_F);
#pragma unroll
        for (int j = 0; j < 4; ++j) {
          const int col = wave * 64 + j * 16 + l15;
          const int row = bm + lr;
          const float x = cacc[i][j][r];
          t[(size_t)row * 256 + col] = x;
          Hout[(size_t)row * 256 + col] = __float2bfloat16(
              (x - m) * rr * g[col] + bb[col]);
        }
      }
  } else {
#pragma unroll
    for (int i = 0; i < 4; ++i)
#pragma unroll
      for (int j = 0; j < 4; ++j) {
        const int col = wave * 64 + j * 16 + l15;
#pragma unroll
        for (int r = 0; r < 4; ++r) {
          const int row = bm + i * 16 + rb + r;
          t[(size_t)row * 256 + col] = cacc[i][j][r];
        }
      }
  }
}

// ---------------------------------------------------------------------------
extern "C" void kernel_launch(void* const* d_in, const int* in_sizes, int n_in,
                              void* d_out, int out_size, void* d_ws, size_t ws_size,
                              hipStream_t stream) {
  const float* x        = (const float*)d_in[0];
  const float* W_patch  = (const float*)d_in[1];
  const float* b_patch  = (const float*)d_in[2];
  const float* ln1_g    = (const float*)d_in[3];
  const float* ln1_b    = (const float*)d_in[4];
  const float* Wqkv     = (const float*)d_in[5];
  const float* headsita = (const float*)d_in[6];
  const float* bias_tbl = (const float*)d_in[7];
  const float* Wout     = (const float*)d_in[8];
  const float* bout     = (const float*)d_in[9];
  const float* ln2_g    = (const float*)d_in[10];
  const float* ln2_b    = (const float*)d_in[11];
  const float* W1       = (const float*)d_in[12];
  const float* b1       = (const float*)d_in[13];
  const float* W2       = (const float*)d_in[14];
  const float* b2       = (const float*)d_in[15];

  char* W = (char*)d_ws;
  float*  t   = (float*)W;                       // [65536,256] f32, 64 MB
  ushort* h   = (ushort*)(W + 67108864);         // [65536,256] bf16, 32 MB
  ushort* Xg  = (ushort*)(W + 100663296);        // [65536,256] bf16 (patch input)
  ushort* wT  = (ushort*)(W + 234881024);        // transposed bf16 weights

  ushort* WpT   = wT;
  ushort* WqkvT = wT + 65536;
  ushort* WoutT = wT + 458752;
  ushort* W1T   = wT + 589824;
  ushort* W2T   = wT + 1114112;

  float* out_img = (float*)d_out;
  float* attns   = out_img + 16777216;

  transpose_all_k<<<1600, 256, 0, stream>>>(
      W_patch, Wqkv, Wout, W1, W2, WpT, WqkvT, WoutT, W1T, W2T);

  gather_k<<<2048, 256, 0, stream>>>(x, Xg);
  mm_ln_k<false><<<1024, 256, 0, stream>>>(
      Xg, WpT, b_patch, nullptr, t, (__hip_bfloat16*)h, ln1_g, ln1_b, 256);

  for (int l = 0; l < 2; ++l) {
    attn_fused2_k<<<1024, 512, 0, stream>>>(
        h, WqkvT + (size_t)l * 196608, WoutT + (size_t)l * 65536,
        bout + l * 256, t, (__hip_bfloat16*)h, ln2_g + l * 256, ln2_b + l * 256,
        attns + (size_t)l * 33554432,
        bias_tbl + l * 225 * NHEADS, headsita + l * NHEADS);
    if (l == 0) {
      mlp_fused_k<true><<<1024, 256, 0, stream>>>(
          h, W1T, b1, W2T, b2, t, (__hip_bfloat16*)h, ln1_g + 256, ln1_b + 256);
    } else {
      mlp_fused_k<false><<<1024, 256, 0, stream>>>(
          h, W1T + 262144, b1 + MLP_N, W2T + 262144, b2 + 256, t,
          nullptr, nullptr, nullptr);
    }
  }

  unwindow_k<<<2048, 256, 0, stream>>>(t, out_img);
}